// Round 9
// baseline (105.723 us; speedup 1.0000x reference)
//
#include <hip/hip_runtime.h>

// Problem: BATCH=8192, DIM=4096 units, SUB=2.
// ref: o = (x_slice @ W1[u]) @ W2[u]; p = f32 softmax(o); out = one_hot(argmax(p)).
//
// CORRECTNESS MODEL (verified: rounds 5/6/8 PASS, absmax = 0.0):
//  1. f32 einsum chain round-per-op (mul, mul, add; NO fma), h materialized
//     in f32 — numpy semantics. __f*_rn blocks -ffp-contract=fast.
//  2. softmax decision with t = fl(o1-o0):
//       argmax 1  <=>  (t > 0) && (__fsub_rn(1.0f, t) < 1.0f)
//     (np expf on tiny args reduces to fl(1-t); boundary t=2^-25 round-to-even
//     -> tie -> argmax 0. Do NOT use device expf — different boundary.)
//
// PERF LOG: r5 naive grid-stride: 129.6us (4.14 TB/s). r6 weights-in-VGPR:
// 115.3us (4.66). r8 nt loads/stores + 4-deep bursts: 104.9us (5.12 = 81% of
// the 6.29 TB/s measured copy ceiling). r9 (this): 8-deep bursts — 8KB
// same-direction per wave per burst to amortize HBM read/write turnaround —
// plus u32 byte-offset addressing (buffer = 2^28 B fits 32 bits).

#define BATCH 8192
#define DIMU  4096
#define NPAIR (DIMU / 2)                       // 2048 unit-pairs (one float4 of x each)
#define NX    ((size_t)BATCH * DIMU * 2)       // 67108864
#define ROWS  32                               // batch rows per thread
#define NTHREADS ((size_t)BATCH * NPAIR / ROWS)  // 524288 threads total
#define ROWB  (NPAIR * 16u)                    // bytes per batch row = 32768

typedef float f32x4 __attribute__((ext_vector_type(4)));

__device__ __forceinline__ float2 unit_onehot(float x0, float x1,
                                              f32x4 w1, f32x4 w2) {
    // W layout (in,out): w.x=W[0][0], w.y=W[0][1], w.z=W[1][0], w.w=W[1][1]
    const float h0 = __fadd_rn(__fmul_rn(x0, w1.x), __fmul_rn(x1, w1.z));
    const float h1 = __fadd_rn(__fmul_rn(x0, w1.y), __fmul_rn(x1, w1.w));
    const float o0 = __fadd_rn(__fmul_rn(h0, w2.x), __fmul_rn(h1, w2.z));
    const float o1 = __fadd_rn(__fmul_rn(h0, w2.y), __fmul_rn(h1, w2.w));
    const float t  = __fsub_rn(o1, o0);
    const bool one = (t > 0.0f) && (__fsub_rn(1.0f, t) < 1.0f);
    return make_float2(one ? 0.0f : 1.0f, one ? 1.0f : 0.0f);
}

__device__ __forceinline__ f32x4 pair_onehot(f32x4 xv, f32x4 w1a, f32x4 w2a,
                                             f32x4 w1b, f32x4 w2b) {
    const float2 ra = unit_onehot(xv.x, xv.y, w1a, w2a);
    const float2 rb = unit_onehot(xv.z, xv.w, w1b, w2b);
    f32x4 ov;
    ov.x = ra.x; ov.y = ra.y; ov.z = rb.x; ov.w = rb.y;
    return ov;
}

__global__ __launch_bounds__(256) void onehot_units_kernel(
    const float* __restrict__ x,
    const float* __restrict__ W1,
    const float* __restrict__ W2,
    float* __restrict__ out)
{
    const unsigned gid = blockIdx.x * blockDim.x + threadIdx.x;   // < 524288
    const unsigned p     = gid & (NPAIR - 1);      // unit-pair this thread owns
    const unsigned chunk = gid >> 11;              // which 32-row batch chunk

    const f32x4* __restrict__ w1_4 = reinterpret_cast<const f32x4*>(W1);
    const f32x4* __restrict__ w2_4 = reinterpret_cast<const f32x4*>(W2);

    // Weights for units 2p, 2p+1 — loaded ONCE via cache (reused data).
    const f32x4 w1a = w1_4[2 * p];
    const f32x4 w1b = w1_4[2 * p + 1];
    const f32x4 w2a = w2_4[2 * p];
    const f32x4 w2b = w2_4[2 * p + 1];

    // u32 byte offsets: whole stream is 2^28 B. Per-row stride 32KB.
    unsigned off = chunk * (ROWS * ROWB) + p * 16u;
    const char* __restrict__ xb = reinterpret_cast<const char*>(x);
    char* __restrict__ ob = reinterpret_cast<char*>(out);

    #pragma unroll
    for (int g = 0; g < ROWS / 8; ++g, off += 8 * ROWB) {
        // burst of 8 nontemporal loads (8KB same-direction per wave)
        f32x4 v[8];
        #pragma unroll
        for (int k = 0; k < 8; ++k)
            v[k] = __builtin_nontemporal_load(
                reinterpret_cast<const f32x4*>(xb + off + k * ROWB));
        #pragma unroll
        for (int k = 0; k < 8; ++k)
            v[k] = pair_onehot(v[k], w1a, w2a, w1b, w2b);
        // burst of 8 nontemporal stores
        #pragma unroll
        for (int k = 0; k < 8; ++k)
            __builtin_nontemporal_store(
                v[k], reinterpret_cast<f32x4*>(ob + off + k * ROWB));
    }
}

extern "C" void kernel_launch(void* const* d_in, const int* in_sizes, int n_in,
                              void* d_out, int out_size, void* d_ws, size_t ws_size,
                              hipStream_t stream) {
    // Default: setup_inputs() dict order {x, W1, W2}.
    const float* x  = (const float*)d_in[0];
    const float* W1 = (const float*)d_in[1];
    const float* W2 = (const float*)d_in[2];
    // Hardened input identification (validated by the round-4 diagnostic):
    // x is the uniquely-big input; W1 precedes W2 among the small inputs.
    if (n_in >= 3) {
        int xi = -1;
        for (int k = 0; k < 3; ++k) if (in_sizes[k] == (int)NX) xi = k;
        if (xi >= 0) {
            int wi = -1, wj = -1;
            for (int k = 0; k < 3; ++k) if (k != xi) { if (wi < 0) wi = k; else wj = k; }
            x  = (const float*)d_in[xi];
            W1 = (const float*)d_in[wi];
            W2 = (const float*)d_in[wj];
        }
    }
    float* out = (float*)d_out;

    // 524288 threads: one unit-pair x 32 batch rows each. 2048 blocks x 256.
    dim3 grid((unsigned)(NTHREADS / 256)), block(256);
    hipLaunchKernelGGL(onehot_units_kernel, grid, block, 0, stream,
                       x, W1, W2, out);
}